// Round 6
// baseline (134.761 us; speedup 1.0000x reference)
//
#include <hip/hip_runtime.h>
#include <hip/hip_bf16.h>
#include <math.h>

#define D_MODEL 512
#define D_LOW   64
#define NBINS   39
#define LOG2E   1.4426950408889634f
#define LN2     0.6931471805599453f

typedef __attribute__((ext_vector_type(8))) short short8;
typedef __attribute__((ext_vector_type(4))) float floatx4;

// ---------------------------------------------------------------------------
// Kernel 1, role A (blocks [0, nLN)): LN+projection MFMA GEMM with prep fold
// on the fly. Role B (blocks [nLN, nLN+TB)): target-bin precompute -> int8.
// ---------------------------------------------------------------------------
__global__ __launch_bounds__(256) void lnproj_tbin_kernel(
    const float* __restrict__ h_res,
    const float* __restrict__ ln_w, const float* __restrict__ ln_b,
    const float* __restrict__ wu_w, const float* __restrict__ wu_b,
    const float* __restrict__ wv_w, const float* __restrict__ wv_b,
    const float* __restrict__ x_true, const float* __restrict__ pmask,
    float* __restrict__ U, __hip_bfloat16* __restrict__ Vbf,
    signed char* __restrict__ tbg, int N, int B, int nLN, int TB) {
  const int tid = threadIdx.x;

  if ((int)blockIdx.x >= nLN) {
    const int idx   = blockIdx.x - nLN;
    const int NN    = N * N;
    const int total = B * NN;
    const float BW  = (22.0f - 2.0f) / 38.0f;
    for (int p = idx * 256 + tid; p < total; p += TB * 256) {
      const int b = p / NN;
      const int r = p - b * NN;
      const int i = r / N;
      const int j = r - i * N;
      const int rowi = b * N + i, rowj = b * N + j;
      const float dx = x_true[rowi * 3 + 0] - x_true[rowj * 3 + 0];
      const float dy = x_true[rowi * 3 + 1] - x_true[rowj * 3 + 1];
      const float dz = x_true[rowi * 3 + 2] - x_true[rowj * 3 + 2];
      const float d  = sqrtf(dx * dx + dy * dy + dz * dz);
      int tb = (int)((d - 2.0f) / BW);
      tb = tb < 0 ? 0 : (tb > NBINS - 1 ? NBINS - 1 : tb);
      const bool ok = (pmask[rowi] * pmask[rowj]) > 0.f;
      tbg[p] = ok ? (signed char)tb : (signed char)-1;
    }
    return;
  }

  const int wave = tid >> 6, lane = tid & 63;
  const int q = lane >> 4, ln16 = lane & 15;
  const int row0 = blockIdx.x * 16;
  const float* hp = h_res + (size_t)(row0 + ln16) * D_MODEL + q * 8;

  short8 abf[16];
  float sum = 0.f, ssq = 0.f;
  #pragma unroll
  for (int kc = 0; kc < 16; ++kc) {
    const floatx4 x0 = *reinterpret_cast<const floatx4*>(hp + kc * 32);
    const floatx4 x1 = *reinterpret_cast<const floatx4*>(hp + kc * 32 + 4);
    short8 a;
    #pragma unroll
    for (int e = 0; e < 4; ++e) {
      sum += x0[e]; ssq += x0[e] * x0[e];
      const __hip_bfloat16 hb = __float2bfloat16(x0[e]);
      a[e] = *reinterpret_cast<const short*>(&hb);
    }
    #pragma unroll
    for (int e = 0; e < 4; ++e) {
      sum += x1[e]; ssq += x1[e] * x1[e];
      const __hip_bfloat16 hb = __float2bfloat16(x1[e]);
      a[4 + e] = *reinterpret_cast<const short*>(&hb);
    }
    abf[kc] = a;
  }
  sum += __shfl_xor(sum, 16); sum += __shfl_xor(sum, 32);
  ssq += __shfl_xor(ssq, 16); ssq += __shfl_xor(ssq, 32);
  const float mu  = sum * (1.0f / (float)D_MODEL);
  const float var = ssq * (1.0f / (float)D_MODEL) - mu * mu;
  const float rs  = rsqrtf(var + 1e-5f);
  float mu_r[4], rs_r[4];
  #pragma unroll
  for (int r = 0; r < 4; ++r) {
    mu_r[r] = __shfl(mu, q * 4 + r);
    rs_r[r] = __shfl(rs, q * 4 + r);
  }

  const int obase = wave * 32;
  const int out0 = obase + ln16;
  const int out1 = obase + 16 + ln16;
  const float* wr0 = (out0 < 64) ? (wu_w + out0 * D_MODEL) : (wv_w + (out0 - 64) * D_MODEL);
  const float* wr1 = (out1 < 64) ? (wu_w + out1 * D_MODEL) : (wv_w + (out1 - 64) * D_MODEL);
  const float sc0 = (out0 < 64) ? LOG2E : 1.0f;
  const float sc1 = (out1 < 64) ? LOG2E : 1.0f;

  floatx4 acc0 = (floatx4){0.f, 0.f, 0.f, 0.f};
  floatx4 acc1 = (floatx4){0.f, 0.f, 0.f, 0.f};
  float s1a = 0.f, s1b = 0.f;
  float s2a = 0.f, s2b = 0.f;
  #pragma unroll
  for (int kc = 0; kc < 16; ++kc) {
    const int c0 = kc * 32 + q * 8;
    const floatx4 lw0 = *reinterpret_cast<const floatx4*>(ln_w + c0);
    const floatx4 lw1 = *reinterpret_cast<const floatx4*>(ln_w + c0 + 4);
    const floatx4 lb0 = *reinterpret_cast<const floatx4*>(ln_b + c0);
    const floatx4 lb1 = *reinterpret_cast<const floatx4*>(ln_b + c0 + 4);
    const floatx4 wa0 = *reinterpret_cast<const floatx4*>(wr0 + c0);
    const floatx4 wa1 = *reinterpret_cast<const floatx4*>(wr0 + c0 + 4);
    const floatx4 wb0 = *reinterpret_cast<const floatx4*>(wr1 + c0);
    const floatx4 wb1 = *reinterpret_cast<const floatx4*>(wr1 + c0 + 4);
    short8 b0, b1;
    #pragma unroll
    for (int e = 0; e < 4; ++e) {
      const float v0 = wa0[e] * lw0[e] * sc0;
      const float v1 = wa1[e] * lw1[e] * sc0;
      const __hip_bfloat16 h0 = __float2bfloat16(v0);
      const __hip_bfloat16 h1 = __float2bfloat16(v1);
      b0[e]     = *reinterpret_cast<const short*>(&h0);
      b0[4 + e] = *reinterpret_cast<const short*>(&h1);
      s1a += __bfloat162float(h0) + __bfloat162float(h1);
      s2a += wa0[e] * lb0[e] + wa1[e] * lb1[e];
      const float u0 = wb0[e] * lw0[e] * sc1;
      const float u1 = wb1[e] * lw1[e] * sc1;
      const __hip_bfloat16 g0 = __float2bfloat16(u0);
      const __hip_bfloat16 g1 = __float2bfloat16(u1);
      b1[e]     = *reinterpret_cast<const short*>(&g0);
      b1[4 + e] = *reinterpret_cast<const short*>(&g1);
      s1b += __bfloat162float(g0) + __bfloat162float(g1);
      s2b += wb0[e] * lb0[e] + wb1[e] * lb1[e];
    }
    acc0 = __builtin_amdgcn_mfma_f32_16x16x32_bf16(abf[kc], b0, acc0, 0, 0, 0);
    acc1 = __builtin_amdgcn_mfma_f32_16x16x32_bf16(abf[kc], b1, acc1, 0, 0, 0);
  }
  s1a += __shfl_xor(s1a, 16); s1a += __shfl_xor(s1a, 32);
  s1b += __shfl_xor(s1b, 16); s1b += __shfl_xor(s1b, 32);
  s2a += __shfl_xor(s2a, 16); s2a += __shfl_xor(s2a, 32);
  s2b += __shfl_xor(s2b, 16); s2b += __shfl_xor(s2b, 32);
  const float bias0 = sc0 * (((out0 < 64) ? wu_b[out0] : wv_b[out0 - 64]) + s2a);
  const float bias1 = sc1 * (((out1 < 64) ? wu_b[out1] : wv_b[out1 - 64]) + s2b);

  #pragma unroll
  for (int nt = 0; nt < 2; ++nt) {
    const int out  = nt ? out1 : out0;
    const floatx4 a = nt ? acc1 : acc0;
    const float ws = nt ? s1b : s1a;
    const float bb = nt ? bias1 : bias0;
    #pragma unroll
    for (int r = 0; r < 4; ++r) {
      const int rowg = row0 + q * 4 + r;
      const float val = rs_r[r] * a[r] - mu_r[r] * rs_r[r] * ws + bb;
      if (out < 64) {
        U[(size_t)rowg * D_LOW + out] = val;
      } else {
        Vbf[(size_t)rowg * D_LOW + (out - 64)] = __float2bfloat16(val);
      }
    }
  }
}

// ---------------------------------------------------------------------------
// Kernel 2: pair stage v3. Grid (N, 2*B): blockIdx.y -> (b, j-half).
// Wave owns 96 j's (3 groups of 32), software-pipelined one group ahead.
// MFMA C-operand pre-initialized with scaled biases (-inf pads). Target-
// logit pick via single inline-const v_cmp per slot (tbq = tb - 4q).
// ---------------------------------------------------------------------------
__global__ __launch_bounds__(256) void pair_mfma_kernel(
    const float* __restrict__ U,                 // prescaled by log2e
    const __hip_bfloat16* __restrict__ Vbf,      // [BN][64] bf16
    const float* __restrict__ wb_w, const float* __restrict__ wb_b,
    const signed char* __restrict__ tbg,
    float* __restrict__ part, int N) {
  __shared__ float rbuf[8];
  const int i    = blockIdx.x;
  const int b    = blockIdx.y >> 1;
  const int half = blockIdx.y & 1;
  const int tid  = threadIdx.x;
  const int wave = tid >> 6, lane = tid & 63;
  const int q = lane >> 4, ln16 = lane & 15;
  const int rowi = b * N + i;

  // Build W2_i fragments (A operand): W2[n][c] = bf16(U2[c] * wb_w[n][c])
  short8 wfrag[3][2];
  {
    const float* Up = U + (size_t)rowi * D_LOW;
    #pragma unroll
    for (int t = 0; t < 3; ++t) {
      const int n = t * 16 + ln16;
      #pragma unroll
      for (int s = 0; s < 2; ++s) {
        const int c0 = s * 32 + q * 8;
        short8 f;
        #pragma unroll
        for (int e = 0; e < 8; ++e) {
          const float w = (n < NBINS) ? wb_w[n * D_LOW + c0 + e] : 0.f;
          const float v = Up[c0 + e] * w;
          const __hip_bfloat16 hb = __float2bfloat16(v);
          f[e] = *reinterpret_cast<const short*>(&hb);
        }
        wfrag[t][s] = f;
      }
    }
  }

  // MFMA C-init: scaled bias per slot, -inf on pad slots (exp2 -> 0)
  floatx4 bias_init[3];
  #pragma unroll
  for (int t = 0; t < 3; ++t)
    #pragma unroll
    for (int r = 0; r < 4; ++r) {
      const int bin = t * 16 + q * 4 + r;
      bias_init[t][r] = (bin < NBINS) ? LOG2E * wb_b[bin] : -INFINITY;
    }

  const short* Vp = reinterpret_cast<const short*>(Vbf) + (size_t)b * N * D_LOW;
  const signed char* tbp = tbg + (size_t)b * N * N + (size_t)i * N;
  const int jbase = half * 384 + wave * 96;
  const int q4 = q * 4;

  float ce_sum = 0.f, cnt_sum = 0.f;

  short8 v[2][2];
  int tbv[2];
  {
    #pragma unroll
    for (int tt = 0; tt < 2; ++tt) {
      const size_t jr = jbase + tt * 16 + ln16;
      v[tt][0] = *reinterpret_cast<const short8*>(Vp + jr * D_LOW + q * 8);
      v[tt][1] = *reinterpret_cast<const short8*>(Vp + jr * D_LOW + 32 + q * 8);
      tbv[tt]  = (int)tbp[jr];
    }
  }

  for (int g = 0; g < 3; ++g) {
    // Prefetch next group before the epilogue of this one
    short8 vn[2][2];
    int tbn[2];
    if (g < 2) {
      const int jb = jbase + (g + 1) * 32;
      #pragma unroll
      for (int tt = 0; tt < 2; ++tt) {
        const size_t jr = jb + tt * 16 + ln16;
        vn[tt][0] = *reinterpret_cast<const short8*>(Vp + jr * D_LOW + q * 8);
        vn[tt][1] = *reinterpret_cast<const short8*>(Vp + jr * D_LOW + 32 + q * 8);
        tbn[tt]   = (int)tbp[jr];
      }
    }

    floatx4 f[2][3];
    #pragma unroll
    for (int tt = 0; tt < 2; ++tt)
      #pragma unroll
      for (int t = 0; t < 3; ++t) {
        floatx4 a = bias_init[t];
        a = __builtin_amdgcn_mfma_f32_16x16x32_bf16(wfrag[t][0], v[tt][0], a, 0, 0, 0);
        a = __builtin_amdgcn_mfma_f32_16x16x32_bf16(wfrag[t][1], v[tt][1], a, 0, 0, 0);
        f[tt][t] = a;
      }

    #pragma unroll
    for (int tt = 0; tt < 2; ++tt) {
      const int tb  = tbv[tt];
      const int tbq = tb - q4;          // slot match: tbq == t*16 + r
      float s0 = 0.f, s1 = 0.f, s2 = 0.f, s3 = 0.f, lt = 0.f;
      #pragma unroll
      for (int t = 0; t < 3; ++t) {
        const floatx4 fv = f[tt][t];
        s0 += __builtin_amdgcn_exp2f(fv[0]);
        s1 += __builtin_amdgcn_exp2f(fv[1]);
        s2 += __builtin_amdgcn_exp2f(fv[2]);
        s3 += __builtin_amdgcn_exp2f(fv[3]);
        lt += (tbq == t * 16 + 0) ? fv[0] : 0.f;
        lt += (tbq == t * 16 + 1) ? fv[1] : 0.f;
        lt += (tbq == t * 16 + 2) ? fv[2] : 0.f;
        lt += (tbq == t * 16 + 3) ? fv[3] : 0.f;
      }
      float ssum = (s0 + s1) + (s2 + s3);
      ssum += __shfl_xor(ssum, 16); ssum += __shfl_xor(ssum, 32);
      // x4-quad identity: Σ_quads [log2(ssum) - 4*lt_local] = 4*CE/ln2
      const float ok = (tb >= 0) ? 1.f : 0.f;
      ce_sum  += ok * LN2 * (__builtin_amdgcn_logf(ssum) - 4.0f * lt);
      cnt_sum += ok;
    }

    if (g < 2) {
      #pragma unroll
      for (int tt = 0; tt < 2; ++tt) {
        v[tt][0] = vn[tt][0]; v[tt][1] = vn[tt][1]; tbv[tt] = tbn[tt];
      }
    }
  }

  #pragma unroll
  for (int off = 32; off; off >>= 1) {
    ce_sum  += __shfl_xor(ce_sum, off);
    cnt_sum += __shfl_xor(cnt_sum, off);
  }
  if (lane == 0) { rbuf[wave] = ce_sum; rbuf[4 + wave] = cnt_sum; }
  __syncthreads();
  if (tid == 0) {
    const size_t slot = ((size_t)(b * 2 + half) * N + i) * 2;
    part[slot + 0] = rbuf[0] + rbuf[1] + rbuf[2] + rbuf[3];
    part[slot + 1] = rbuf[4] + rbuf[5] + rbuf[6] + rbuf[7];
  }
}

// ---------------------------------------------------------------------------
// Kernel 3: finalize — batch b owns 2N contiguous partial slots.
// ---------------------------------------------------------------------------
__global__ __launch_bounds__(256) void finalize_kernel(
    const float* __restrict__ part, float* __restrict__ out, int N, int B) {
  __shared__ float red[8];
  const int tid = threadIdx.x, wave = tid >> 6, lane = tid & 63;
  float loss = 0.f, vcount = 0.f;
  for (int b = 0; b < B; ++b) {
    float ce = 0.f, cnt = 0.f;
    for (int e = tid; e < 2 * N; e += 256) {
      const size_t base = ((size_t)b * 2 * N + e) * 2;
      ce  += part[base + 0];
      cnt += part[base + 1];
    }
    #pragma unroll
    for (int off = 32; off; off >>= 1) {
      ce  += __shfl_xor(ce, off);
      cnt += __shfl_xor(cnt, off);
    }
    if (lane == 0) { red[wave] = ce; red[4 + wave] = cnt; }
    __syncthreads();
    if (tid == 0) {
      const float s = red[0] + red[1] + red[2] + red[3];
      const float c = red[4] + red[5] + red[6] + red[7];
      if (c > 0.f) { loss += s / fmaxf(c, 1.f); vcount += 1.f; }
    }
    __syncthreads();
  }
  if (tid == 0) out[0] = (vcount > 0.f) ? loss / vcount : 0.f;
}

extern "C" void kernel_launch(void* const* d_in, const int* in_sizes, int n_in,
                              void* d_out, int out_size, void* d_ws, size_t ws_size,
                              hipStream_t stream) {
  const float* h_res  = (const float*)d_in[0];
  const float* x_true = (const float*)d_in[1];
  const float* pmask  = (const float*)d_in[2];
  const float* ln_w   = (const float*)d_in[3];
  const float* ln_b   = (const float*)d_in[4];
  const float* wu_w   = (const float*)d_in[5];
  const float* wu_b   = (const float*)d_in[6];
  const float* wv_w   = (const float*)d_in[7];
  const float* wv_b   = (const float*)d_in[8];
  const float* wb_w   = (const float*)d_in[9];
  const float* wb_b   = (const float*)d_in[10];

  const int B  = 2;
  const int N  = in_sizes[2] / B;
  const int BN = B * N;
  const int nLN = BN / 16;     // 96 lnproj blocks
  const int TB  = 160;         // tbin blocks

  // ws: U f32[BN*64] | Vbf bf16[BN*64] | part f32[4*BN] | tbg s8[B*N*N]
  float* U = (float*)d_ws;
  __hip_bfloat16* Vbf = (__hip_bfloat16*)(U + (size_t)BN * D_LOW);
  float* part = (float*)(Vbf + (size_t)BN * D_LOW);
  signed char* tbg = (signed char*)(part + 4 * (size_t)BN);

  lnproj_tbin_kernel<<<nLN + TB, 256, 0, stream>>>(
      h_res, ln_w, ln_b, wu_w, wu_b, wv_w, wv_b, x_true, pmask,
      U, Vbf, tbg, N, B, nLN, TB);
  pair_mfma_kernel<<<dim3(N, 2 * B), 256, 0, stream>>>(U, Vbf, wb_w, wb_b,
                                                       tbg, part, N);
  finalize_kernel<<<1, 256, 0, stream>>>(part, (float*)d_out, N, B);
}

// Round 7
// 125.603 us; speedup vs baseline: 1.0729x; 1.0729x over previous
//
#include <hip/hip_runtime.h>
#include <hip/hip_bf16.h>
#include <math.h>

#define D_MODEL 512
#define D_LOW   64
#define NBINS   39
#define LOG2E   1.4426950408889634f
#define LN2     0.6931471805599453f

typedef __attribute__((ext_vector_type(8))) short short8;
typedef __attribute__((ext_vector_type(4))) float floatx4;

// ---------------------------------------------------------------------------
// Kernel 1, role A (blocks [0, nLN)): LN+projection MFMA GEMM with prep fold
// on the fly. Role B (blocks [nLN, nLN+TB)): target-bin precompute -> int8.
// ---------------------------------------------------------------------------
__global__ __launch_bounds__(256) void lnproj_tbin_kernel(
    const float* __restrict__ h_res,
    const float* __restrict__ ln_w, const float* __restrict__ ln_b,
    const float* __restrict__ wu_w, const float* __restrict__ wu_b,
    const float* __restrict__ wv_w, const float* __restrict__ wv_b,
    const float* __restrict__ x_true, const float* __restrict__ pmask,
    float* __restrict__ U, __hip_bfloat16* __restrict__ Vbf,
    signed char* __restrict__ tbg, int N, int B, int nLN, int TB) {
  const int tid = threadIdx.x;

  if ((int)blockIdx.x >= nLN) {
    const int idx   = blockIdx.x - nLN;
    const int NN    = N * N;
    const int total = B * NN;
    const float BW  = (22.0f - 2.0f) / 38.0f;
    for (int p = idx * 256 + tid; p < total; p += TB * 256) {
      const int b = p / NN;
      const int r = p - b * NN;
      const int i = r / N;
      const int j = r - i * N;
      const int rowi = b * N + i, rowj = b * N + j;
      const float dx = x_true[rowi * 3 + 0] - x_true[rowj * 3 + 0];
      const float dy = x_true[rowi * 3 + 1] - x_true[rowj * 3 + 1];
      const float dz = x_true[rowi * 3 + 2] - x_true[rowj * 3 + 2];
      const float d  = sqrtf(dx * dx + dy * dy + dz * dz);
      int tb = (int)((d - 2.0f) / BW);
      tb = tb < 0 ? 0 : (tb > NBINS - 1 ? NBINS - 1 : tb);
      const bool ok = (pmask[rowi] * pmask[rowj]) > 0.f;
      tbg[p] = ok ? (signed char)tb : (signed char)-1;
    }
    return;
  }

  const int wave = tid >> 6, lane = tid & 63;
  const int q = lane >> 4, ln16 = lane & 15;
  const int row0 = blockIdx.x * 16;
  const float* hp = h_res + (size_t)(row0 + ln16) * D_MODEL + q * 8;

  short8 abf[16];
  float sum = 0.f, ssq = 0.f;
  #pragma unroll
  for (int kc = 0; kc < 16; ++kc) {
    const floatx4 x0 = *reinterpret_cast<const floatx4*>(hp + kc * 32);
    const floatx4 x1 = *reinterpret_cast<const floatx4*>(hp + kc * 32 + 4);
    short8 a;
    #pragma unroll
    for (int e = 0; e < 4; ++e) {
      sum += x0[e]; ssq += x0[e] * x0[e];
      const __hip_bfloat16 hb = __float2bfloat16(x0[e]);
      a[e] = *reinterpret_cast<const short*>(&hb);
    }
    #pragma unroll
    for (int e = 0; e < 4; ++e) {
      sum += x1[e]; ssq += x1[e] * x1[e];
      const __hip_bfloat16 hb = __float2bfloat16(x1[e]);
      a[4 + e] = *reinterpret_cast<const short*>(&hb);
    }
    abf[kc] = a;
  }
  sum += __shfl_xor(sum, 16); sum += __shfl_xor(sum, 32);
  ssq += __shfl_xor(ssq, 16); ssq += __shfl_xor(ssq, 32);
  const float mu  = sum * (1.0f / (float)D_MODEL);
  const float var = ssq * (1.0f / (float)D_MODEL) - mu * mu;
  const float rs  = rsqrtf(var + 1e-5f);
  float mu_r[4], rs_r[4];
  #pragma unroll
  for (int r = 0; r < 4; ++r) {
    mu_r[r] = __shfl(mu, q * 4 + r);
    rs_r[r] = __shfl(rs, q * 4 + r);
  }

  const int obase = wave * 32;
  const int out0 = obase + ln16;
  const int out1 = obase + 16 + ln16;
  const float* wr0 = (out0 < 64) ? (wu_w + out0 * D_MODEL) : (wv_w + (out0 - 64) * D_MODEL);
  const float* wr1 = (out1 < 64) ? (wu_w + out1 * D_MODEL) : (wv_w + (out1 - 64) * D_MODEL);
  const float sc0 = (out0 < 64) ? LOG2E : 1.0f;
  const float sc1 = (out1 < 64) ? LOG2E : 1.0f;

  floatx4 acc0 = (floatx4){0.f, 0.f, 0.f, 0.f};
  floatx4 acc1 = (floatx4){0.f, 0.f, 0.f, 0.f};
  float s1a = 0.f, s1b = 0.f;
  float s2a = 0.f, s2b = 0.f;
  #pragma unroll
  for (int kc = 0; kc < 16; ++kc) {
    const int c0 = kc * 32 + q * 8;
    const floatx4 lw0 = *reinterpret_cast<const floatx4*>(ln_w + c0);
    const floatx4 lw1 = *reinterpret_cast<const floatx4*>(ln_w + c0 + 4);
    const floatx4 lb0 = *reinterpret_cast<const floatx4*>(ln_b + c0);
    const floatx4 lb1 = *reinterpret_cast<const floatx4*>(ln_b + c0 + 4);
    const floatx4 wa0 = *reinterpret_cast<const floatx4*>(wr0 + c0);
    const floatx4 wa1 = *reinterpret_cast<const floatx4*>(wr0 + c0 + 4);
    const floatx4 wb0 = *reinterpret_cast<const floatx4*>(wr1 + c0);
    const floatx4 wb1 = *reinterpret_cast<const floatx4*>(wr1 + c0 + 4);
    short8 b0, b1;
    #pragma unroll
    for (int e = 0; e < 4; ++e) {
      const float v0 = wa0[e] * lw0[e] * sc0;
      const float v1 = wa1[e] * lw1[e] * sc0;
      const __hip_bfloat16 h0 = __float2bfloat16(v0);
      const __hip_bfloat16 h1 = __float2bfloat16(v1);
      b0[e]     = *reinterpret_cast<const short*>(&h0);
      b0[4 + e] = *reinterpret_cast<const short*>(&h1);
      s1a += __bfloat162float(h0) + __bfloat162float(h1);
      s2a += wa0[e] * lb0[e] + wa1[e] * lb1[e];
      const float u0 = wb0[e] * lw0[e] * sc1;
      const float u1 = wb1[e] * lw1[e] * sc1;
      const __hip_bfloat16 g0 = __float2bfloat16(u0);
      const __hip_bfloat16 g1 = __float2bfloat16(u1);
      b1[e]     = *reinterpret_cast<const short*>(&g0);
      b1[4 + e] = *reinterpret_cast<const short*>(&g1);
      s1b += __bfloat162float(g0) + __bfloat162float(g1);
      s2b += wb0[e] * lb0[e] + wb1[e] * lb1[e];
    }
    acc0 = __builtin_amdgcn_mfma_f32_16x16x32_bf16(abf[kc], b0, acc0, 0, 0, 0);
    acc1 = __builtin_amdgcn_mfma_f32_16x16x32_bf16(abf[kc], b1, acc1, 0, 0, 0);
  }
  s1a += __shfl_xor(s1a, 16); s1a += __shfl_xor(s1a, 32);
  s1b += __shfl_xor(s1b, 16); s1b += __shfl_xor(s1b, 32);
  s2a += __shfl_xor(s2a, 16); s2a += __shfl_xor(s2a, 32);
  s2b += __shfl_xor(s2b, 16); s2b += __shfl_xor(s2b, 32);
  const float bias0 = sc0 * (((out0 < 64) ? wu_b[out0] : wv_b[out0 - 64]) + s2a);
  const float bias1 = sc1 * (((out1 < 64) ? wu_b[out1] : wv_b[out1 - 64]) + s2b);

  #pragma unroll
  for (int nt = 0; nt < 2; ++nt) {
    const int out  = nt ? out1 : out0;
    const floatx4 a = nt ? acc1 : acc0;
    const float ws = nt ? s1b : s1a;
    const float bb = nt ? bias1 : bias0;
    #pragma unroll
    for (int r = 0; r < 4; ++r) {
      const int rowg = row0 + q * 4 + r;
      const float val = rs_r[r] * a[r] - mu_r[r] * rs_r[r] * ws + bb;
      if (out < 64) {
        U[(size_t)rowg * D_LOW + out] = val;
      } else {
        Vbf[(size_t)rowg * D_LOW + (out - 64)] = __float2bfloat16(val);
      }
    }
  }
}

// ---------------------------------------------------------------------------
// Kernel 1.5 (wprep): build each (b,i)'s 6 MFMA A-operand fragments ONCE.
//   wfragbuf[rowi][f][lane][8] shorts, f = t*2+s  (lane-major -> the pair
//   kernel reads them as 6 perfectly-coalesced dwordx4 loads).
// wb_w staged to LDS with stride-65 padding (kills 16-way bank aliasing on
// the n-indexed reads). 4 rows per block (one per wave), grid = BN/4.
// ---------------------------------------------------------------------------
__global__ __launch_bounds__(256) void wprep_kernel(
    const float* __restrict__ U, const float* __restrict__ wb_w,
    short* __restrict__ wfragbuf, int BN) {
  __shared__ float wsh[NBINS * 65];
  const int tid = threadIdx.x;
  for (int e = tid; e < NBINS * D_LOW; e += 256) {
    const int n = e >> 6, c = e & 63;
    wsh[n * 65 + c] = wb_w[e];
  }
  __syncthreads();

  const int wave = tid >> 6, lane = tid & 63;
  const int q = lane >> 4, ln16 = lane & 15;
  const int rowi = blockIdx.x * 4 + wave;
  const float* Up = U + (size_t)rowi * D_LOW;

  float u[16];
  #pragma unroll
  for (int s = 0; s < 2; ++s)
    #pragma unroll
    for (int e = 0; e < 8; ++e) u[s * 8 + e] = Up[s * 32 + q * 8 + e];

  short* outp = wfragbuf + (size_t)rowi * 6 * 64 * 8;
  #pragma unroll
  for (int t = 0; t < 3; ++t) {
    const int n = t * 16 + ln16;
    #pragma unroll
    for (int s = 0; s < 2; ++s) {
      short8 f;
      #pragma unroll
      for (int e = 0; e < 8; ++e) {
        const float w = (n < NBINS) ? wsh[n * 65 + s * 32 + q * 8 + e] : 0.f;
        const float v = u[s * 8 + e] * w;
        const __hip_bfloat16 hb = __float2bfloat16(v);
        f[e] = *reinterpret_cast<const short*>(&hb);
      }
      *reinterpret_cast<short8*>(outp + ((size_t)(t * 2 + s) * 64 + lane) * 8) = f;
    }
  }
}

// ---------------------------------------------------------------------------
// Kernel 2: pair stage v4. Identical main loop to round 6 (prefetch pipeline,
// bias-in-C, grid (N, 2*B)); ONLY change: setup reads precomputed fragments
// via 6 coalesced dwordx4 loads instead of 48 address-divergent wb_w gathers.
// ---------------------------------------------------------------------------
__global__ __launch_bounds__(256) void pair_mfma_kernel(
    const short* __restrict__ wfragbuf,          // [BN][6][64][8] shorts
    const __hip_bfloat16* __restrict__ Vbf,      // [BN][64] bf16
    const float* __restrict__ wb_b,
    const signed char* __restrict__ tbg,
    float* __restrict__ part, int N) {
  __shared__ float rbuf[8];
  const int i    = blockIdx.x;
  const int b    = blockIdx.y >> 1;
  const int half = blockIdx.y & 1;
  const int tid  = threadIdx.x;
  const int wave = tid >> 6, lane = tid & 63;
  const int q = lane >> 4, ln16 = lane & 15;
  const int rowi = b * N + i;

  // Setup: 6 coalesced fragment loads
  short8 wfrag[3][2];
  {
    const short* wfp = wfragbuf + (size_t)rowi * 6 * 64 * 8;
    #pragma unroll
    for (int t = 0; t < 3; ++t)
      #pragma unroll
      for (int s = 0; s < 2; ++s)
        wfrag[t][s] = *reinterpret_cast<const short8*>(
            wfp + ((size_t)(t * 2 + s) * 64 + lane) * 8);
  }

  // MFMA C-init: scaled bias per slot, -inf on pad slots (exp2 -> 0)
  floatx4 bias_init[3];
  #pragma unroll
  for (int t = 0; t < 3; ++t)
    #pragma unroll
    for (int r = 0; r < 4; ++r) {
      const int bin = t * 16 + q * 4 + r;
      bias_init[t][r] = (bin < NBINS) ? LOG2E * wb_b[bin] : -INFINITY;
    }

  const short* Vp = reinterpret_cast<const short*>(Vbf) + (size_t)b * N * D_LOW;
  const signed char* tbp = tbg + (size_t)b * N * N + (size_t)i * N;
  const int jbase = half * 384 + wave * 96;
  const int q4 = q * 4;

  float ce_sum = 0.f, cnt_sum = 0.f;

  short8 v[2][2];
  int tbv[2];
  {
    #pragma unroll
    for (int tt = 0; tt < 2; ++tt) {
      const size_t jr = jbase + tt * 16 + ln16;
      v[tt][0] = *reinterpret_cast<const short8*>(Vp + jr * D_LOW + q * 8);
      v[tt][1] = *reinterpret_cast<const short8*>(Vp + jr * D_LOW + 32 + q * 8);
      tbv[tt]  = (int)tbp[jr];
    }
  }

  for (int g = 0; g < 3; ++g) {
    short8 vn[2][2];
    int tbn[2];
    if (g < 2) {
      const int jb = jbase + (g + 1) * 32;
      #pragma unroll
      for (int tt = 0; tt < 2; ++tt) {
        const size_t jr = jb + tt * 16 + ln16;
        vn[tt][0] = *reinterpret_cast<const short8*>(Vp + jr * D_LOW + q * 8);
        vn[tt][1] = *reinterpret_cast<const short8*>(Vp + jr * D_LOW + 32 + q * 8);
        tbn[tt]   = (int)tbp[jr];
      }
    }

    floatx4 f[2][3];
    #pragma unroll
    for (int tt = 0; tt < 2; ++tt)
      #pragma unroll
      for (int t = 0; t < 3; ++t) {
        floatx4 a = bias_init[t];
        a = __builtin_amdgcn_mfma_f32_16x16x32_bf16(wfrag[t][0], v[tt][0], a, 0, 0, 0);
        a = __builtin_amdgcn_mfma_f32_16x16x32_bf16(wfrag[t][1], v[tt][1], a, 0, 0, 0);
        f[tt][t] = a;
      }

    #pragma unroll
    for (int tt = 0; tt < 2; ++tt) {
      const int tb  = tbv[tt];
      const int tbq = tb - q4;
      float s0 = 0.f, s1 = 0.f, s2 = 0.f, s3 = 0.f, lt = 0.f;
      #pragma unroll
      for (int t = 0; t < 3; ++t) {
        const floatx4 fv = f[tt][t];
        s0 += __builtin_amdgcn_exp2f(fv[0]);
        s1 += __builtin_amdgcn_exp2f(fv[1]);
        s2 += __builtin_amdgcn_exp2f(fv[2]);
        s3 += __builtin_amdgcn_exp2f(fv[3]);
        lt += (tbq == t * 16 + 0) ? fv[0] : 0.f;
        lt += (tbq == t * 16 + 1) ? fv[1] : 0.f;
        lt += (tbq == t * 16 + 2) ? fv[2] : 0.f;
        lt += (tbq == t * 16 + 3) ? fv[3] : 0.f;
      }
      float ssum = (s0 + s1) + (s2 + s3);
      ssum += __shfl_xor(ssum, 16); ssum += __shfl_xor(ssum, 32);
      const float ok = (tb >= 0) ? 1.f : 0.f;
      ce_sum  += ok * LN2 * (__builtin_amdgcn_logf(ssum) - 4.0f * lt);
      cnt_sum += ok;
    }

    if (g < 2) {
      #pragma unroll
      for (int tt = 0; tt < 2; ++tt) {
        v[tt][0] = vn[tt][0]; v[tt][1] = vn[tt][1]; tbv[tt] = tbn[tt];
      }
    }
  }

  #pragma unroll
  for (int off = 32; off; off >>= 1) {
    ce_sum  += __shfl_xor(ce_sum, off);
    cnt_sum += __shfl_xor(cnt_sum, off);
  }
  if (lane == 0) { rbuf[wave] = ce_sum; rbuf[4 + wave] = cnt_sum; }
  __syncthreads();
  if (tid == 0) {
    const size_t slot = ((size_t)(b * 2 + half) * N + i) * 2;
    part[slot + 0] = rbuf[0] + rbuf[1] + rbuf[2] + rbuf[3];
    part[slot + 1] = rbuf[4] + rbuf[5] + rbuf[6] + rbuf[7];
  }
}

// ---------------------------------------------------------------------------
// Kernel 3: finalize — batch b owns 2N contiguous partial slots.
// ---------------------------------------------------------------------------
__global__ __launch_bounds__(256) void finalize_kernel(
    const float* __restrict__ part, float* __restrict__ out, int N, int B) {
  __shared__ float red[8];
  const int tid = threadIdx.x, wave = tid >> 6, lane = tid & 63;
  float loss = 0.f, vcount = 0.f;
  for (int b = 0; b < B; ++b) {
    float ce = 0.f, cnt = 0.f;
    for (int e = tid; e < 2 * N; e += 256) {
      const size_t base = ((size_t)b * 2 * N + e) * 2;
      ce  += part[base + 0];
      cnt += part[base + 1];
    }
    #pragma unroll
    for (int off = 32; off; off >>= 1) {
      ce  += __shfl_xor(ce, off);
      cnt += __shfl_xor(cnt, off);
    }
    if (lane == 0) { red[wave] = ce; red[4 + wave] = cnt; }
    __syncthreads();
    if (tid == 0) {
      const float s = red[0] + red[1] + red[2] + red[3];
      const float c = red[4] + red[5] + red[6] + red[7];
      if (c > 0.f) { loss += s / fmaxf(c, 1.f); vcount += 1.f; }
    }
    __syncthreads();
  }
  if (tid == 0) out[0] = (vcount > 0.f) ? loss / vcount : 0.f;
}

extern "C" void kernel_launch(void* const* d_in, const int* in_sizes, int n_in,
                              void* d_out, int out_size, void* d_ws, size_t ws_size,
                              hipStream_t stream) {
  const float* h_res  = (const float*)d_in[0];
  const float* x_true = (const float*)d_in[1];
  const float* pmask  = (const float*)d_in[2];
  const float* ln_w   = (const float*)d_in[3];
  const float* ln_b   = (const float*)d_in[4];
  const float* wu_w   = (const float*)d_in[5];
  const float* wu_b   = (const float*)d_in[6];
  const float* wv_w   = (const float*)d_in[7];
  const float* wv_b   = (const float*)d_in[8];
  const float* wb_w   = (const float*)d_in[9];
  const float* wb_b   = (const float*)d_in[10];

  const int B  = 2;
  const int N  = in_sizes[2] / B;
  const int BN = B * N;
  const int nLN = BN / 16;     // 96 lnproj blocks
  const int TB  = 160;         // tbin blocks

  // ws: U f32[BN*64] | Vbf bf16[BN*64] | part f32[4*BN] | tbg s8[B*N*N]
  //     | wfragbuf short[BN*6*64*8]
  float* U = (float*)d_ws;
  __hip_bfloat16* Vbf = (__hip_bfloat16*)(U + (size_t)BN * D_LOW);
  float* part = (float*)(Vbf + (size_t)BN * D_LOW);
  signed char* tbg = (signed char*)(part + 4 * (size_t)BN);
  short* wfragbuf = (short*)(tbg + (size_t)B * N * N);

  lnproj_tbin_kernel<<<nLN + TB, 256, 0, stream>>>(
      h_res, ln_w, ln_b, wu_w, wu_b, wv_w, wv_b, x_true, pmask,
      U, Vbf, tbg, N, B, nLN, TB);
  wprep_kernel<<<BN / 4, 256, 0, stream>>>(U, wb_w, wfragbuf, BN);
  pair_mfma_kernel<<<dim3(N, 2 * B), 256, 0, stream>>>(wfragbuf, Vbf, wb_b,
                                                       tbg, part, N);
  finalize_kernel<<<1, 256, 0, stream>>>(part, (float*)d_out, N, B);
}

// Round 8
// 118.507 us; speedup vs baseline: 1.1372x; 1.0599x over previous
//
#include <hip/hip_runtime.h>
#include <hip/hip_bf16.h>
#include <math.h>

#define D_MODEL 512
#define D_LOW   64
#define NBINS   39
#define LOG2E   1.4426950408889634f
#define LN2     0.6931471805599453f

typedef __attribute__((ext_vector_type(8))) short short8;
typedef __attribute__((ext_vector_type(4))) float floatx4;

// ---------------------------------------------------------------------------
// Kernel A (combo), 1D grid = 128 + B*N blocks.
// Blocks [0,128): prep — fold LN affine + log2e into projection weights:
//   w2bf[o][c] = bf16(w[o][c]*ln_w[c]*scale), w2sum[o] = sum_c (bf16-rounded),
//   b2[o] = scale*(b[o] + sum_c w[o][c]*ln_b[c]),  scale = log2e for U half.
// Blocks [128, 128+B*N): tbin — target bins for row i of batch b, division-
// free (b,i from block id), x_true[i] wave-uniform, j coalesced.
// ---------------------------------------------------------------------------
__global__ __launch_bounds__(256) void prep_tbin_kernel(
    const float* __restrict__ ln_w, const float* __restrict__ ln_b,
    const float* __restrict__ wu_w, const float* __restrict__ wu_b,
    const float* __restrict__ wv_w, const float* __restrict__ wv_b,
    const float* __restrict__ x_true, const float* __restrict__ pmask,
    __hip_bfloat16* __restrict__ w2bf, float* __restrict__ w2sum,
    float* __restrict__ b2, signed char* __restrict__ tbg, int N) {
  const int tid = threadIdx.x;

  if ((int)blockIdx.x >= 128) {
    // ---- tbin role ----
    const int p = blockIdx.x - 128;
    const int b = (p >= N) ? 1 : 0;          // B == 2
    const int i = p - b * N;
    const int rowi = b * N + i;
    const float xi0 = x_true[rowi * 3 + 0];
    const float xi1 = x_true[rowi * 3 + 1];
    const float xi2 = x_true[rowi * 3 + 2];
    const float pmi = pmask[rowi];
    const float BW  = (22.0f - 2.0f) / 38.0f;
    signed char* tbp = tbg + (size_t)b * N * N + (size_t)i * N;
    for (int j = tid; j < N; j += 256) {
      const int rowj = b * N + j;
      const float dx = xi0 - x_true[rowj * 3 + 0];
      const float dy = xi1 - x_true[rowj * 3 + 1];
      const float dz = xi2 - x_true[rowj * 3 + 2];
      const float d  = sqrtf(dx * dx + dy * dy + dz * dz);
      int tb = (int)((d - 2.0f) / BW);
      tb = tb < 0 ? 0 : (tb > NBINS - 1 ? NBINS - 1 : tb);
      tbp[j] = (pmi * pmask[rowj] > 0.f) ? (signed char)tb : (signed char)-1;
    }
    return;
  }

  // ---- prep role ----
  __shared__ float red[8];
  const int o = blockIdx.x;
  const bool isU = (o < 64);
  const float* wrow = isU ? (wu_w + o * D_MODEL) : (wv_w + (o - 64) * D_MODEL);
  const float scale = isU ? LOG2E : 1.0f;

  float s1 = 0.f, s2 = 0.f;
  #pragma unroll
  for (int cc = 0; cc < 2; ++cc) {
    const int c = tid + cc * 256;
    const float w  = wrow[c];
    const float w2 = w * ln_w[c] * scale;
    const __hip_bfloat16 hb = __float2bfloat16(w2);
    w2bf[o * D_MODEL + c] = hb;
    s1 += __bfloat162float(hb);
    s2 += w * ln_b[c];
  }
  #pragma unroll
  for (int off = 32; off; off >>= 1) {
    s1 += __shfl_xor(s1, off);
    s2 += __shfl_xor(s2, off);
  }
  const int wave = tid >> 6, lane = tid & 63;
  if (lane == 0) { red[wave] = s1; red[4 + wave] = s2; }
  __syncthreads();
  if (tid == 0) {
    w2sum[o] = red[0] + red[1] + red[2] + red[3];
    const float ss2 = red[4] + red[5] + red[6] + red[7];
    b2[o] = scale * ((isU ? wu_b[o] : wv_b[o - 64]) + ss2);
  }
}

// ---------------------------------------------------------------------------
// Kernel B (lnproj): one wave per block, grid = (BN/16) * 4.
// Block = 16 rows x 32 outs (out-group og = blockIdx & 3). Reads pre-folded
// bf16 weights (2 short8 loads + 2 MFMA per k-step), LN applied in epilogue.
// ---------------------------------------------------------------------------
__global__ __launch_bounds__(64) void lnproj_kernel(
    const float* __restrict__ h_res, const __hip_bfloat16* __restrict__ w2bf,
    const float* __restrict__ w2sum, const float* __restrict__ b2,
    float* __restrict__ U, __hip_bfloat16* __restrict__ Vbf, int N) {
  const int lane = threadIdx.x;
  const int q = lane >> 4, ln16 = lane & 15;
  const int rt = blockIdx.x >> 2, og = blockIdx.x & 3;
  const int row0 = rt * 16;
  const float* hp = h_res + (size_t)(row0 + ln16) * D_MODEL + q * 8;

  short8 abf[16];
  float sum = 0.f, ssq = 0.f;
  #pragma unroll
  for (int kc = 0; kc < 16; ++kc) {
    const floatx4 x0 = *reinterpret_cast<const floatx4*>(hp + kc * 32);
    const floatx4 x1 = *reinterpret_cast<const floatx4*>(hp + kc * 32 + 4);
    short8 a;
    #pragma unroll
    for (int e = 0; e < 4; ++e) {
      sum += x0[e]; ssq += x0[e] * x0[e];
      const __hip_bfloat16 hb = __float2bfloat16(x0[e]);
      a[e] = *reinterpret_cast<const short*>(&hb);
    }
    #pragma unroll
    for (int e = 0; e < 4; ++e) {
      sum += x1[e]; ssq += x1[e] * x1[e];
      const __hip_bfloat16 hb = __float2bfloat16(x1[e]);
      a[4 + e] = *reinterpret_cast<const short*>(&hb);
    }
    abf[kc] = a;
  }
  sum += __shfl_xor(sum, 16); sum += __shfl_xor(sum, 32);
  ssq += __shfl_xor(ssq, 16); ssq += __shfl_xor(ssq, 32);
  const float mu  = sum * (1.0f / (float)D_MODEL);
  const float var = ssq * (1.0f / (float)D_MODEL) - mu * mu;
  const float rs  = rsqrtf(var + 1e-5f);
  float mu_r[4], rs_r[4];
  #pragma unroll
  for (int r = 0; r < 4; ++r) {
    mu_r[r] = __shfl(mu, q * 4 + r);
    rs_r[r] = __shfl(rs, q * 4 + r);
  }

  const int obase = og * 32;
  const int out0 = obase + ln16;
  const int out1 = obase + 16 + ln16;
  const short* wp = reinterpret_cast<const short*>(w2bf);
  floatx4 acc0 = (floatx4){0.f, 0.f, 0.f, 0.f};
  floatx4 acc1 = (floatx4){0.f, 0.f, 0.f, 0.f};
  #pragma unroll
  for (int kc = 0; kc < 16; ++kc) {
    const short8 b0 = *reinterpret_cast<const short8*>(
        wp + (size_t)out0 * D_MODEL + kc * 32 + q * 8);
    const short8 b1 = *reinterpret_cast<const short8*>(
        wp + (size_t)out1 * D_MODEL + kc * 32 + q * 8);
    acc0 = __builtin_amdgcn_mfma_f32_16x16x32_bf16(abf[kc], b0, acc0, 0, 0, 0);
    acc1 = __builtin_amdgcn_mfma_f32_16x16x32_bf16(abf[kc], b1, acc1, 0, 0, 0);
  }

  #pragma unroll
  for (int nt = 0; nt < 2; ++nt) {
    const int out  = nt ? out1 : out0;
    const floatx4 a = nt ? acc1 : acc0;
    const float ws = w2sum[out];
    const float bb = b2[out];
    #pragma unroll
    for (int r = 0; r < 4; ++r) {
      const int rowg = row0 + q * 4 + r;
      const float val = rs_r[r] * a[r] - mu_r[r] * rs_r[r] * ws + bb;
      if (out < 64) {
        U[(size_t)rowg * D_LOW + out] = val;
      } else {
        Vbf[(size_t)rowg * D_LOW + (out - 64)] = __float2bfloat16(val);
      }
    }
  }
}

// ---------------------------------------------------------------------------
// Kernel 1.5 (wprep): build each (b,i)'s 6 MFMA A-operand fragments ONCE.
// wb_w staged to LDS with stride-65 padding. 4 rows/block, grid = BN/4.
// ---------------------------------------------------------------------------
__global__ __launch_bounds__(256) void wprep_kernel(
    const float* __restrict__ U, const float* __restrict__ wb_w,
    short* __restrict__ wfragbuf, int BN) {
  __shared__ float wsh[NBINS * 65];
  const int tid = threadIdx.x;
  for (int e = tid; e < NBINS * D_LOW; e += 256) {
    const int n = e >> 6, c = e & 63;
    wsh[n * 65 + c] = wb_w[e];
  }
  __syncthreads();

  const int wave = tid >> 6, lane = tid & 63;
  const int q = lane >> 4, ln16 = lane & 15;
  const int rowi = blockIdx.x * 4 + wave;
  const float* Up = U + (size_t)rowi * D_LOW;

  float u[16];
  #pragma unroll
  for (int s = 0; s < 2; ++s)
    #pragma unroll
    for (int e = 0; e < 8; ++e) u[s * 8 + e] = Up[s * 32 + q * 8 + e];

  short* outp = wfragbuf + (size_t)rowi * 6 * 64 * 8;
  #pragma unroll
  for (int t = 0; t < 3; ++t) {
    const int n = t * 16 + ln16;
    #pragma unroll
    for (int s = 0; s < 2; ++s) {
      short8 f;
      #pragma unroll
      for (int e = 0; e < 8; ++e) {
        const float w = (n < NBINS) ? wsh[n * 65 + s * 32 + q * 8 + e] : 0.f;
        const float v = u[s * 8 + e] * w;
        const __hip_bfloat16 hb = __float2bfloat16(v);
        f[e] = *reinterpret_cast<const short*>(&hb);
      }
      *reinterpret_cast<short8*>(outp + ((size_t)(t * 2 + s) * 64 + lane) * 8) = f;
    }
  }
}

// ---------------------------------------------------------------------------
// Kernel 2: pair stage (unchanged from round 7).
// ---------------------------------------------------------------------------
__global__ __launch_bounds__(256) void pair_mfma_kernel(
    const short* __restrict__ wfragbuf,          // [BN][6][64][8] shorts
    const __hip_bfloat16* __restrict__ Vbf,      // [BN][64] bf16
    const float* __restrict__ wb_b,
    const signed char* __restrict__ tbg,
    float* __restrict__ part, int N) {
  __shared__ float rbuf[8];
  const int i    = blockIdx.x;
  const int b    = blockIdx.y >> 1;
  const int half = blockIdx.y & 1;
  const int tid  = threadIdx.x;
  const int wave = tid >> 6, lane = tid & 63;
  const int q = lane >> 4, ln16 = lane & 15;
  const int rowi = b * N + i;

  short8 wfrag[3][2];
  {
    const short* wfp = wfragbuf + (size_t)rowi * 6 * 64 * 8;
    #pragma unroll
    for (int t = 0; t < 3; ++t)
      #pragma unroll
      for (int s = 0; s < 2; ++s)
        wfrag[t][s] = *reinterpret_cast<const short8*>(
            wfp + ((size_t)(t * 2 + s) * 64 + lane) * 8);
  }

  floatx4 bias_init[3];
  #pragma unroll
  for (int t = 0; t < 3; ++t)
    #pragma unroll
    for (int r = 0; r < 4; ++r) {
      const int bin = t * 16 + q * 4 + r;
      bias_init[t][r] = (bin < NBINS) ? LOG2E * wb_b[bin] : -INFINITY;
    }

  const short* Vp = reinterpret_cast<const short*>(Vbf) + (size_t)b * N * D_LOW;
  const signed char* tbp = tbg + (size_t)b * N * N + (size_t)i * N;
  const int jbase = half * 384 + wave * 96;
  const int q4 = q * 4;

  float ce_sum = 0.f, cnt_sum = 0.f;

  short8 v[2][2];
  int tbv[2];
  {
    #pragma unroll
    for (int tt = 0; tt < 2; ++tt) {
      const size_t jr = jbase + tt * 16 + ln16;
      v[tt][0] = *reinterpret_cast<const short8*>(Vp + jr * D_LOW + q * 8);
      v[tt][1] = *reinterpret_cast<const short8*>(Vp + jr * D_LOW + 32 + q * 8);
      tbv[tt]  = (int)tbp[jr];
    }
  }

  for (int g = 0; g < 3; ++g) {
    short8 vn[2][2];
    int tbn[2];
    if (g < 2) {
      const int jb = jbase + (g + 1) * 32;
      #pragma unroll
      for (int tt = 0; tt < 2; ++tt) {
        const size_t jr = jb + tt * 16 + ln16;
        vn[tt][0] = *reinterpret_cast<const short8*>(Vp + jr * D_LOW + q * 8);
        vn[tt][1] = *reinterpret_cast<const short8*>(Vp + jr * D_LOW + 32 + q * 8);
        tbn[tt]   = (int)tbp[jr];
      }
    }

    floatx4 f[2][3];
    #pragma unroll
    for (int tt = 0; tt < 2; ++tt)
      #pragma unroll
      for (int t = 0; t < 3; ++t) {
        floatx4 a = bias_init[t];
        a = __builtin_amdgcn_mfma_f32_16x16x32_bf16(wfrag[t][0], v[tt][0], a, 0, 0, 0);
        a = __builtin_amdgcn_mfma_f32_16x16x32_bf16(wfrag[t][1], v[tt][1], a, 0, 0, 0);
        f[tt][t] = a;
      }

    #pragma unroll
    for (int tt = 0; tt < 2; ++tt) {
      const int tb  = tbv[tt];
      const int tbq = tb - q4;
      float s0 = 0.f, s1 = 0.f, s2 = 0.f, s3 = 0.f, lt = 0.f;
      #pragma unroll
      for (int t = 0; t < 3; ++t) {
        const floatx4 fv = f[tt][t];
        s0 += __builtin_amdgcn_exp2f(fv[0]);
        s1 += __builtin_amdgcn_exp2f(fv[1]);
        s2 += __builtin_amdgcn_exp2f(fv[2]);
        s3 += __builtin_amdgcn_exp2f(fv[3]);
        lt += (tbq == t * 16 + 0) ? fv[0] : 0.f;
        lt += (tbq == t * 16 + 1) ? fv[1] : 0.f;
        lt += (tbq == t * 16 + 2) ? fv[2] : 0.f;
        lt += (tbq == t * 16 + 3) ? fv[3] : 0.f;
      }
      float ssum = (s0 + s1) + (s2 + s3);
      ssum += __shfl_xor(ssum, 16); ssum += __shfl_xor(ssum, 32);
      const float ok = (tb >= 0) ? 1.f : 0.f;
      ce_sum  += ok * LN2 * (__builtin_amdgcn_logf(ssum) - 4.0f * lt);
      cnt_sum += ok;
    }

    if (g < 2) {
      #pragma unroll
      for (int tt = 0; tt < 2; ++tt) {
        v[tt][0] = vn[tt][0]; v[tt][1] = vn[tt][1]; tbv[tt] = tbn[tt];
      }
    }
  }

  #pragma unroll
  for (int off = 32; off; off >>= 1) {
    ce_sum  += __shfl_xor(ce_sum, off);
    cnt_sum += __shfl_xor(cnt_sum, off);
  }
  if (lane == 0) { rbuf[wave] = ce_sum; rbuf[4 + wave] = cnt_sum; }
  __syncthreads();
  if (tid == 0) {
    const size_t slot = ((size_t)(b * 2 + half) * N + i) * 2;
    part[slot + 0] = rbuf[0] + rbuf[1] + rbuf[2] + rbuf[3];
    part[slot + 1] = rbuf[4] + rbuf[5] + rbuf[6] + rbuf[7];
  }
}

// ---------------------------------------------------------------------------
// Kernel 3: finalize — batch b owns 2N contiguous partial slots.
// ---------------------------------------------------------------------------
__global__ __launch_bounds__(256) void finalize_kernel(
    const float* __restrict__ part, float* __restrict__ out, int N, int B) {
  __shared__ float red[8];
  const int tid = threadIdx.x, wave = tid >> 6, lane = tid & 63;
  float loss = 0.f, vcount = 0.f;
  for (int b = 0; b < B; ++b) {
    float ce = 0.f, cnt = 0.f;
    for (int e = tid; e < 2 * N; e += 256) {
      const size_t base = ((size_t)b * 2 * N + e) * 2;
      ce  += part[base + 0];
      cnt += part[base + 1];
    }
    #pragma unroll
    for (int off = 32; off; off >>= 1) {
      ce  += __shfl_xor(ce, off);
      cnt += __shfl_xor(cnt, off);
    }
    if (lane == 0) { red[wave] = ce; red[4 + wave] = cnt; }
    __syncthreads();
    if (tid == 0) {
      const float s = red[0] + red[1] + red[2] + red[3];
      const float c = red[4] + red[5] + red[6] + red[7];
      if (c > 0.f) { loss += s / fmaxf(c, 1.f); vcount += 1.f; }
    }
    __syncthreads();
  }
  if (tid == 0) out[0] = (vcount > 0.f) ? loss / vcount : 0.f;
}

extern "C" void kernel_launch(void* const* d_in, const int* in_sizes, int n_in,
                              void* d_out, int out_size, void* d_ws, size_t ws_size,
                              hipStream_t stream) {
  const float* h_res  = (const float*)d_in[0];
  const float* x_true = (const float*)d_in[1];
  const float* pmask  = (const float*)d_in[2];
  const float* ln_w   = (const float*)d_in[3];
  const float* ln_b   = (const float*)d_in[4];
  const float* wu_w   = (const float*)d_in[5];
  const float* wu_b   = (const float*)d_in[6];
  const float* wv_w   = (const float*)d_in[7];
  const float* wv_b   = (const float*)d_in[8];
  const float* wb_w   = (const float*)d_in[9];
  const float* wb_b   = (const float*)d_in[10];

  const int B  = 2;
  const int N  = in_sizes[2] / B;
  const int BN = B * N;

  // ws: U f32[BN*64] | Vbf bf16[BN*64] | part f32[4*BN] | tbg s8[B*N*N]
  //     | wfragbuf short[BN*6*64*8] | w2bf bf16[128*512] | w2sum f32[128]
  //     | b2 f32[128]
  float* U = (float*)d_ws;
  __hip_bfloat16* Vbf = (__hip_bfloat16*)(U + (size_t)BN * D_LOW);
  float* part = (float*)(Vbf + (size_t)BN * D_LOW);
  signed char* tbg = (signed char*)(part + 4 * (size_t)BN);
  short* wfragbuf = (short*)(tbg + (size_t)B * N * N);
  __hip_bfloat16* w2bf = (__hip_bfloat16*)(wfragbuf + (size_t)BN * 6 * 64 * 8);
  float* w2sum = (float*)(w2bf + 128 * D_MODEL);
  float* b2    = w2sum + 128;

  prep_tbin_kernel<<<128 + BN, 256, 0, stream>>>(
      ln_w, ln_b, wu_w, wu_b, wv_w, wv_b, x_true, pmask,
      w2bf, w2sum, b2, tbg, N);
  lnproj_kernel<<<(BN / 16) * 4, 64, 0, stream>>>(h_res, w2bf, w2sum, b2,
                                                  U, Vbf, N);
  wprep_kernel<<<BN / 4, 256, 0, stream>>>(U, wb_w, wfragbuf, BN);
  pair_mfma_kernel<<<dim3(N, 2 * B), 256, 0, stream>>>(wfragbuf, Vbf, wb_b,
                                                       tbg, part, N);
  finalize_kernel<<<1, 256, 0, stream>>>(part, (float*)d_out, N, B);
}